// Round 1
// baseline (12267.660 us; speedup 1.0000x reference)
//
#include <hip/hip_runtime.h>
#include <math.h>

// Problem constants
#define NTOKEN 15000
#define EMBED  1024
#define HID    1024
#define VDIM   2048
#define MAXLEN 20
#define BATCH  128
#define NOBJ   36
#define TSTEP  19   // MAXLEN - 1

// ---------------------------------------------------------------------------
// Generic tiled f32 GEMM:
//   C[crow?[m]][n] = relu?( acc(A[arow?[m]] @ B^T) + bias?[n] + cadd?[m*ldadd+n] ) * mulvec?[n]
// A: M x K (row-major, lda), optional row gather via arow
// B: N x K (row-major, ldb)  -> computes A @ B^T
// Requires: M % BM == 0, K % 16 == 0. N guarded.
// ---------------------------------------------------------------------------
template<int BM, int BN, int TM, int TN, bool RELU>
__global__ __launch_bounds__(256) void gemm_bt(
    const float* __restrict__ A, int lda, const int* __restrict__ arow,
    const float* __restrict__ B, int ldb,
    float* __restrict__ C, int ldc, const int* __restrict__ crow,
    const float* __restrict__ bias, const float* __restrict__ mulvec,
    const float* __restrict__ cadd, long ldadd,
    int M, int N, int K)
{
    __shared__ float As[16][BM];
    __shared__ float Bs[16][BN];
    const int tid = threadIdx.x;
    const int m0 = blockIdx.y * BM;
    const int n0 = blockIdx.x * BN;
    const int tc = tid % (BN / TN);
    const int tr = tid / (BN / TN);

    float acc[TM][TN];
#pragma unroll
    for (int i = 0; i < TM; i++)
#pragma unroll
        for (int j = 0; j < TN; j++) acc[i][j] = 0.f;

    const int lrow = tid >> 2;
    const int lkq  = tid & 3;

    for (int k0 = 0; k0 < K; k0 += 16) {
        if (tid < BM * 4) {
            int gm = m0 + lrow;
            int ar = arow ? arow[gm] : gm;
            const float4 a4 = *(const float4*)(A + (long)ar * lda + k0 + lkq * 4);
            As[lkq*4+0][lrow] = a4.x;
            As[lkq*4+1][lrow] = a4.y;
            As[lkq*4+2][lrow] = a4.z;
            As[lkq*4+3][lrow] = a4.w;
        }
        {
            int gn = n0 + lrow;  // BN==64: lrow covers 0..63 with 256 threads
            float4 b4 = make_float4(0.f, 0.f, 0.f, 0.f);
            if (gn < N) b4 = *(const float4*)(B + (long)gn * ldb + k0 + lkq * 4);
            Bs[lkq*4+0][lrow] = b4.x;
            Bs[lkq*4+1][lrow] = b4.y;
            Bs[lkq*4+2][lrow] = b4.z;
            Bs[lkq*4+3][lrow] = b4.w;
        }
        __syncthreads();
#pragma unroll
        for (int k = 0; k < 16; k++) {
            float a_reg[TM], b_reg[TN];
#pragma unroll
            for (int i = 0; i < TM; i++) a_reg[i] = As[k][tr*TM + i];
#pragma unroll
            for (int j = 0; j < TN; j++) b_reg[j] = Bs[k][tc*TN + j];
#pragma unroll
            for (int i = 0; i < TM; i++)
#pragma unroll
                for (int j = 0; j < TN; j++) acc[i][j] += a_reg[i] * b_reg[j];
        }
        __syncthreads();
    }

#pragma unroll
    for (int i = 0; i < TM; i++) {
        int m = m0 + tr*TM + i;
#pragma unroll
        for (int j = 0; j < TN; j++) {
            int n = n0 + tc*TN + j;
            if (n < N) {
                float v = acc[i][j];
                if (bias)   v += bias[n];
                if (cadd)   v += cadd[(long)m * ldadd + n];
                if (RELU)   v = fmaxf(v, 0.f);
                if (mulvec) v *= mulvec[n];
                int cm = crow ? crow[m] : m;
                C[(long)cm * ldc + n] = v;
            }
        }
    }
}

// ---------------------------------------------------------------------------
// init: fill token gather indices, C-row scatter indices (b*20+t), zero h1/h2
// ---------------------------------------------------------------------------
__global__ void init_kernel(const int* __restrict__ caption,
                            int* __restrict__ tok_idx, int* __restrict__ crow20,
                            float* __restrict__ h1h2)
{
    int idx = blockIdx.x * 256 + threadIdx.x;
    if (idx < BATCH * TSTEP) {
        int b = idx / TSTEP, t = idx % TSTEP;
        tok_idx[idx] = caption[b * MAXLEN + t];
        crow20[idx]  = b * MAXLEN + t;
    }
    if (idx < 2 * BATCH * HID) h1h2[idx] = 0.f;
}

// Stable descending sort of cap_len (ties by index) -> write caption[:,1:] as f32
__global__ void sort_caption_kernel(const int* __restrict__ caption,
                                    const int* __restrict__ cap_len,
                                    float* __restrict__ out1)
{
    int i = threadIdx.x;
    if (i < BATCH) {
        int li = cap_len[i];
        int rank = 0;
        for (int j = 0; j < BATCH; j++) {
            int lj = cap_len[j];
            if (lj > li || (lj == li && j < i)) rank++;
        }
        for (int k = 0; k < TSTEP; k++)
            out1[rank * TSTEP + k] = (float)caption[i * MAXLEN + 1 + k];
    }
}

__global__ void vmean_kernel(const float* __restrict__ v, float* __restrict__ vmean)
{
    int idx = blockIdx.x * 256 + threadIdx.x;   // BATCH*VDIM
    int b = idx >> 11, d = idx & (VDIM - 1);
    float s = 0.f;
    for (int o = 0; o < NOBJ; o++) s += v[((long)b * NOBJ + o) * VDIM + d];
    vmean[idx] = s * (1.0f / 36.0f);
}

// gi1_static[b,t,:] += gvm[b,:]
__global__ void add_gvm_kernel(float* __restrict__ gi1s, const float* __restrict__ gvm)
{
    long idx = (long)blockIdx.x * 256 + threadIdx.x;  // 2432*3072
    int r = (int)(idx / 3072);
    int n = (int)(idx % 3072);
    int b = r / TSTEP;
    gi1s[idx] += gvm[(long)b * 3072 + n];
}

// GRU gate combine: h = (1-z)*n + z*h
__global__ void gru_kernel(const float* __restrict__ gi, const float* __restrict__ gh,
                           float* __restrict__ hstate,
                           float* __restrict__ hstore, int store_ld)
{
    int idx = blockIdx.x * 256 + threadIdx.x;  // BATCH*HID
    int b = idx >> 10, j = idx & (HID - 1);
    const float* gib = gi + (long)b * 3 * HID;
    const float* ghb = gh + (long)b * 3 * HID;
    float ir = gib[j], iz = gib[HID + j], in_ = gib[2 * HID + j];
    float hr = ghb[j], hz = ghb[HID + j], hn  = ghb[2 * HID + j];
    float r = 1.f / (1.f + expf(-(ir + hr)));
    float z = 1.f / (1.f + expf(-(iz + hz)));
    float n = tanhf(in_ + r * hn);
    float hprev = hstate[idx];
    float hnew = (1.f - z) * n + z * hprev;
    hstate[idx] = hnew;
    if (hstore) hstore[(long)b * store_ld + j] = hnew;
}

// Attention for step t: logits -> softmax(36) -> alpha out, att_v into x2[:, :2048], h copy into x2[:, 2048:]
__global__ __launch_bounds__(256) void attention_kernel(
    const float* __restrict__ vw, const float* __restrict__ q,
    const float* __restrict__ h, const float* __restrict__ v,
    const int* __restrict__ cap_len, int t,
    float* __restrict__ x2, float* __restrict__ alpha)
{
    int b = blockIdx.x;
    __shared__ float logits_s[NOBJ];
    __shared__ float att_s[NOBJ];
    int tid = threadIdx.x;
    int lane = tid & 63, wid = tid >> 6;

    for (int o = wid; o < NOBJ; o += 4) {
        const float* vwo = vw + ((long)b * NOBJ + o) * HID;
        const float* qb = q + (long)b * HID;
        float s = 0.f;
        for (int hh = lane; hh < HID; hh += 64) s += vwo[hh] * qb[hh];
        for (int off = 32; off > 0; off >>= 1) s += __shfl_down(s, off);
        if (lane == 0) logits_s[o] = s;
    }
    __syncthreads();
    if (tid == 0) {
        float mx = logits_s[0];
        for (int o = 1; o < NOBJ; o++) mx = fmaxf(mx, logits_s[o]);
        float sum = 0.f;
        for (int o = 0; o < NOBJ; o++) { float e = expf(logits_s[o] - mx); att_s[o] = e; sum += e; }
        float inv = 1.f / sum;
        for (int o = 0; o < NOBJ; o++) att_s[o] *= inv;
    }
    __syncthreads();
    bool m = (t < cap_len[b] - 1);
    if (tid < NOBJ) alpha[((long)b * MAXLEN + t) * NOBJ + tid] = m ? att_s[tid] : 0.f;
    for (int d = tid; d < VDIM; d += 256) {
        float s = 0.f;
        for (int o = 0; o < NOBJ; o++) s += att_s[o] * v[((long)b * NOBJ + o) * VDIM + d];
        x2[(long)b * 3072 + d] = s;
    }
    for (int d = tid; d < HID; d += 256)
        x2[(long)b * 3072 + VDIM + d] = h[(long)b * HID + d];
}

// Row softmax over NTOKEN in-place on predict; masked rows -> uniform; t==19 alpha row -> 0
__global__ __launch_bounds__(256) void softmax_kernel(float* __restrict__ predict,
                                                      float* __restrict__ alpha,
                                                      const int* __restrict__ cap_len)
{
    __shared__ float sred[4];
    int row = blockIdx.x;                 // 0 .. 2559  (b*20 + t)
    int b = row / MAXLEN, t = row % MAXLEN;
    float* p = predict + (long)row * NTOKEN;
    int tid = threadIdx.x;
    int dec = cap_len[b] - 1;
    if (t >= dec) {
        const float u = 1.0f / (float)NTOKEN;
        for (int i = tid; i < NTOKEN; i += 256) p[i] = u;
        if (t == MAXLEN - 1 && tid < NOBJ) alpha[(long)row * NOBJ + tid] = 0.f;
        return;
    }
    float mx = -3.4e38f;
    for (int i = tid; i < NTOKEN; i += 256) mx = fmaxf(mx, p[i]);
    for (int off = 32; off > 0; off >>= 1) mx = fmaxf(mx, __shfl_down(mx, off));
    if ((tid & 63) == 0) sred[tid >> 6] = mx;
    __syncthreads();
    mx = fmaxf(fmaxf(sred[0], sred[1]), fmaxf(sred[2], sred[3]));
    __syncthreads();
    float s = 0.f;
    for (int i = tid; i < NTOKEN; i += 256) s += expf(p[i] - mx);
    for (int off = 32; off > 0; off >>= 1) s += __shfl_down(s, off);
    if ((tid & 63) == 0) sred[tid >> 6] = s;
    __syncthreads();
    s = sred[0] + sred[1] + sred[2] + sred[3];
    float inv = 1.f / s;
    for (int i = tid; i < NTOKEN; i += 256) p[i] = expf(p[i] - mx) * inv;
}

// ---------------------------------------------------------------------------
extern "C" void kernel_launch(void* const* d_in, const int* in_sizes, int n_in,
                              void* d_out, int out_size, void* d_ws, size_t ws_size,
                              hipStream_t stream)
{
    const float* v       = (const float*)d_in[0];
    const int*   caption = (const int*)  d_in[1];
    const int*   cap_len = (const int*)  d_in[2];
    const float* emb     = (const float*)d_in[3];
    const float* Wih1    = (const float*)d_in[4];
    const float* Whh1    = (const float*)d_in[5];
    const float* bih1    = (const float*)d_in[6];
    const float* bhh1    = (const float*)d_in[7];
    const float* Wih2    = (const float*)d_in[8];
    const float* Whh2    = (const float*)d_in[9];
    const float* bih2    = (const float*)d_in[10];
    const float* bhh2    = (const float*)d_in[11];
    const float* Wfc1    = (const float*)d_in[12];
    const float* bfc1    = (const float*)d_in[13];
    const float* Wfc2    = (const float*)d_in[14];
    const float* bfc2    = (const float*)d_in[15];
    const float* Wv      = (const float*)d_in[16];
    const float* bv      = (const float*)d_in[17];
    const float* Wq      = (const float*)d_in[18];
    const float* bq      = (const float*)d_in[19];
    const float* Wa      = (const float*)d_in[20];
    // ba (d_in[21]) cancels in softmax over objects -> unused

    float* ws = (float*)d_ws;
    // workspace layout (floats)
    const long OFF_VW   = 0;                          // 128*36*1024       = 4718592
    const long OFF_GVM  = OFF_VW   + 4718592;         // 128*3072          = 393216
    const long OFF_GI1S = OFF_GVM  + 393216;          // 2432*3072         = 7471104
    const long OFF_H1   = OFF_GI1S + 7471104;         // 128*1024
    const long OFF_H2   = OFF_H1   + 131072;          // 128*1024
    const long OFF_H    = OFF_H2   + 131072;          // 128*1024
    const long OFF_Q    = OFF_H    + 131072;          // 128*1024
    const long OFF_GI   = OFF_Q    + 131072;          // 128*3072
    const long OFF_GH   = OFF_GI   + 393216;          // 128*3072
    const long OFF_X2   = OFF_GH   + 393216;          // 128*3072
    const long OFF_VM   = OFF_X2   + 393216;          // 128*2048
    const long OFF_H2A  = OFF_VM   + 262144;          // 2432*1024         = 2490368
    const long OFF_INT  = OFF_H2A  + 2490368;         // ints after this

    float* vw_buf = ws + OFF_VW;
    float* gvm    = ws + OFF_GVM;
    float* gi1s   = ws + OFF_GI1S;
    float* h1     = ws + OFF_H1;
    float* h2     = ws + OFF_H2;
    float* hbuf   = ws + OFF_H;
    float* qbuf   = ws + OFF_Q;
    float* gi_buf = ws + OFF_GI;
    float* gh_buf = ws + OFF_GH;
    float* x2     = ws + OFF_X2;
    float* vmean  = ws + OFF_VM;
    float* H2A    = ws + OFF_H2A;
    int* tok_idx  = (int*)(ws + OFF_INT);
    int* crow20   = tok_idx + BATCH * TSTEP;

    float* out     = (float*)d_out;
    float* predict = out;                                       // 128*20*15000
    float* out1    = out + (long)BATCH * MAXLEN * NTOKEN;       // 128*19
    float* alpha   = out1 + (long)BATCH * TSTEP;                // 128*20*36

    // ---- prologue (parallel) ----
    init_kernel<<<1024, 256, 0, stream>>>(caption, tok_idx, crow20, h1 /* h1+h2 contiguous */);
    sort_caption_kernel<<<1, 128, 0, stream>>>(caption, cap_len, out1);
    vmean_kernel<<<(BATCH * VDIM) / 256, 256, 0, stream>>>(v, vmean);

    // vw = relu(v @ Wv^T + bv) * Wa : M=4608, N=1024, K=2048
    gemm_bt<64,64,4,4,true><<<dim3(16, 72), 256, 0, stream>>>(
        v, VDIM, nullptr, Wv, VDIM, vw_buf, HID, nullptr, bv, Wa, nullptr, 0, 4608, HID, VDIM);
    // gvm = v_mean @ Wih1[:,1024:3072]^T + bih1 : M=128, N=3072, K=2048
    gemm_bt<64,64,4,4,false><<<dim3(48, 2), 256, 0, stream>>>(
        vmean, VDIM, nullptr, Wih1 + 1024, 4096, gvm, 3072, nullptr, bih1, nullptr, nullptr, 0, 128, 3072, VDIM);
    // gi1_static = emb[tok] @ Wih1[:,3072:4096]^T : M=2432, N=3072, K=1024
    gemm_bt<64,64,4,4,false><<<dim3(48, 38), 256, 0, stream>>>(
        emb, EMBED, tok_idx, Wih1 + 3072, 4096, gi1s, 3072, nullptr, nullptr, nullptr, nullptr, 0, 2432, 3072, EMBED);
    add_gvm_kernel<<<(2432 * 3072) / 256, 256, 0, stream>>>(gi1s, gvm);

    // ---- recurrent loop ----
    for (int t = 0; t < TSTEP; t++) {
        // gi1 = gi1_static[:,t,:] + h2 @ Wih1[:,0:1024]^T
        gemm_bt<32,64,2,4,false><<<dim3(48, 4), 256, 0, stream>>>(
            h2, HID, nullptr, Wih1, 4096, gi_buf, 3072, nullptr, nullptr, nullptr,
            gi1s + (long)t * 3072, (long)TSTEP * 3072, 128, 3072, HID);
        // gh1 = h1 @ Whh1^T + bhh1
        gemm_bt<32,64,2,4,false><<<dim3(48, 4), 256, 0, stream>>>(
            h1, HID, nullptr, Whh1, HID, gh_buf, 3072, nullptr, bhh1, nullptr, nullptr, 0, 128, 3072, HID);
        gru_kernel<<<512, 256, 0, stream>>>(gi_buf, gh_buf, h1, nullptr, 0);
        // h = h1 @ Wfc1^T + bfc1
        gemm_bt<32,64,2,4,false><<<dim3(16, 4), 256, 0, stream>>>(
            h1, HID, nullptr, Wfc1, HID, hbuf, HID, nullptr, bfc1, nullptr, nullptr, 0, 128, HID, HID);
        // q = relu(h @ Wq^T + bq)
        gemm_bt<32,64,2,4,true><<<dim3(16, 4), 256, 0, stream>>>(
            hbuf, HID, nullptr, Wq, HID, qbuf, HID, nullptr, bq, nullptr, nullptr, 0, 128, HID, HID);
        attention_kernel<<<128, 256, 0, stream>>>(vw_buf, qbuf, hbuf, v, cap_len, t, x2, alpha);
        // gi2 = x2 @ Wih2^T + bih2 : K=3072
        gemm_bt<32,64,2,4,false><<<dim3(48, 4), 256, 0, stream>>>(
            x2, 3072, nullptr, Wih2, 3072, gi_buf, 3072, nullptr, bih2, nullptr, nullptr, 0, 128, 3072, 3072);
        // gh2 = h2 @ Whh2^T + bhh2
        gemm_bt<32,64,2,4,false><<<dim3(48, 4), 256, 0, stream>>>(
            h2, HID, nullptr, Whh2, HID, gh_buf, 3072, nullptr, bhh2, nullptr, nullptr, 0, 128, 3072, HID);
        gru_kernel<<<512, 256, 0, stream>>>(gi_buf, gh_buf, h2, H2A + (long)t * HID, TSTEP * HID);
    }

    // ---- epilogue (parallel) ----
    // logits = H2_all @ Wfc2^T + bfc2 -> scattered into predict rows (b*20+t)
    gemm_bt<64,64,4,4,false><<<dim3(235, 38), 256, 0, stream>>>(
        H2A, HID, nullptr, Wfc2, HID, predict, NTOKEN, crow20, bfc2, nullptr, nullptr, 0, 2432, NTOKEN, HID);
    // in-place softmax + uniform fill of masked rows + zero t=19 alpha rows
    softmax_kernel<<<BATCH * MAXLEN, 256, 0, stream>>>(predict, alpha, cap_len);
}

// Round 2
// 3247.443 us; speedup vs baseline: 3.7776x; 3.7776x over previous
//
#include <hip/hip_runtime.h>
#include <math.h>

#define NTOKEN 15000
#define EMBED  1024
#define HID    1024
#define VDIM   2048
#define MAXLEN 20
#define BATCH  128
#define NOBJ   36
#define TSTEP  19

typedef unsigned short ushort_t;
typedef __attribute__((ext_vector_type(8))) short short8;
typedef __attribute__((ext_vector_type(4))) float floatx4;

__device__ __forceinline__ float b2f(ushort_t u) {
    return __uint_as_float(((unsigned)u) << 16);
}
__device__ __forceinline__ ushort_t f2b(float f) {
    unsigned x = __float_as_uint(f);
    unsigned r = (x + 0x7fffu + ((x >> 16) & 1u)) >> 16;
    return (ushort_t)r;
}

// ---------------------------------------------------------------------------
// MFMA bf16 GEMM core: C[crow?[m]][n] = post( A[arow?[m]] @ B^T )
//   post: +bias[n], +cadd[(m/cadd_div)*ldadd+n], relu if n<relu_n, *mulvec[n]
// A: [M x K] bf16(ushort) row-major (lda); B: [N x K] bf16 row-major (ldb).
// BM = 128 (M % 128 == 0), BN = NF*16, K % 32 == 0. N guarded.
// LDS padded to stride 40 (80 B) -> conflict-free ds_read_b128.
// ---------------------------------------------------------------------------
template<int NF, bool OUT_BF16>
__device__ __forceinline__ void mfma_core(
    ushort_t* As, ushort_t* Bs,
    const ushort_t* __restrict__ A, int lda, const int* __restrict__ arow,
    const ushort_t* __restrict__ B, int ldb,
    void* __restrict__ Cv, int ldc, const int* __restrict__ crow,
    const float* __restrict__ bias, const float* __restrict__ mulvec,
    const float* __restrict__ cadd, long ldadd, int cadd_div,
    int relu_n, int N, int K, int m0, int n0)
{
    const int tid  = threadIdx.x;
    const int lane = tid & 63;
    const int w    = tid >> 6;

    floatx4 acc[2][NF];
#pragma unroll
    for (int mf = 0; mf < 2; mf++)
#pragma unroll
        for (int nf = 0; nf < NF; nf++) acc[mf][nf] = (floatx4){0.f, 0.f, 0.f, 0.f};

    // staging assignment
    const int a_r = tid >> 1;          // 128 rows, 2 threads/row
    const int a_c = (tid & 1) * 16;    // each thread: cols a_c..a_c+15 (2 x 16B)
    const int b_r = tid >> 2;          // up to 64 rows, 4 threads/row
    const int b_c = (tid & 3) * 8;     // 16B each
    int a_g = m0 + a_r;
    if (arow) a_g = arow[a_g];
    int b_g = n0 + b_r;
    if (b_g >= N) b_g = N - 1;
    const ushort_t* Aptr = A + (long)a_g * lda + a_c;
    const ushort_t* Bptr = B + (long)b_g * ldb + b_c;

    uint4 av0 = *(const uint4*)(Aptr);
    uint4 av1 = *(const uint4*)(Aptr + 8);
    uint4 bv  = *(const uint4*)(Bptr);

    const int fr = lane & 15;
    const int q8 = (lane >> 4) * 8;

    for (int kk = 0; kk < K; kk += 32) {
        __syncthreads();
        *(uint4*)(As + a_r * 40 + a_c)     = av0;
        *(uint4*)(As + a_r * 40 + a_c + 8) = av1;
        *(uint4*)(Bs + b_r * 40 + b_c)     = bv;
        if (kk + 32 < K) {
            av0 = *(const uint4*)(Aptr + kk + 32);
            av1 = *(const uint4*)(Aptr + kk + 40);
            bv  = *(const uint4*)(Bptr + kk + 32);
        }
        __syncthreads();
        short8 bfrag[NF];
#pragma unroll
        for (int nf = 0; nf < NF; nf++)
            bfrag[nf] = *(const short8*)(Bs + (nf * 16 + fr) * 40 + q8);
#pragma unroll
        for (int mf = 0; mf < 2; mf++) {
            short8 afrag = *(const short8*)(As + (w * 32 + mf * 16 + fr) * 40 + q8);
#pragma unroll
            for (int nf = 0; nf < NF; nf++)
                acc[mf][nf] = __builtin_amdgcn_mfma_f32_16x16x32_bf16(
                    afrag, bfrag[nf], acc[mf][nf], 0, 0, 0);
        }
    }

    const int rq = lane >> 4;
#pragma unroll
    for (int mf = 0; mf < 2; mf++) {
#pragma unroll
        for (int r = 0; r < 4; r++) {
            int m = m0 + w * 32 + mf * 16 + rq * 4 + r;
            int cm = crow ? crow[m] : m;
            const float* caddrow = cadd ? (cadd + (long)(m / cadd_div) * ldadd) : nullptr;
#pragma unroll
            for (int nf = 0; nf < NF; nf++) {
                int n = n0 + nf * 16 + fr;
                if (n < N) {
                    float val = acc[mf][nf][r];
                    if (bias)    val += bias[n];
                    if (caddrow) val += caddrow[n];
                    if (n < relu_n) val = fmaxf(val, 0.f);
                    if (mulvec)  val *= mulvec[n];
                    if (OUT_BF16) ((ushort_t*)Cv)[(long)cm * ldc + n] = f2b(val);
                    else          ((float*)Cv)[(long)cm * ldc + n]   = val;
                }
            }
        }
    }
}

template<int NF, bool OUT_BF16>
__global__ __launch_bounds__(256) void mfma_gemm(
    const ushort_t* __restrict__ A, int lda, const int* __restrict__ arow,
    const ushort_t* __restrict__ B, int ldb,
    void* __restrict__ C, int ldc, const int* __restrict__ crow,
    const float* __restrict__ bias, const float* __restrict__ mulvec,
    const float* __restrict__ cadd, long ldadd, int cadd_div,
    int relu_n, int N, int K)
{
    __shared__ ushort_t As[128 * 40];
    __shared__ ushort_t Bs[64 * 40];
    mfma_core<NF, OUT_BF16>(As, Bs, A, lda, arow, B, ldb, C, ldc, crow,
                            bias, mulvec, cadd, ldadd, cadd_div, relu_n,
                            N, K, blockIdx.y * 128, blockIdx.x * (NF * 16));
}

// fused per-step GEMM trio: z=0 gi1, z=1 gh1, z=2 gh2 (all M=128, N=3072, K=1024)
template<int NF>
__global__ __launch_bounds__(256) void step3_kernel(
    const ushort_t* __restrict__ h1b, const ushort_t* __restrict__ h2b,
    const ushort_t* __restrict__ Wih1h, const ushort_t* __restrict__ Whh1b,
    const ushort_t* __restrict__ Whh2b,
    float* __restrict__ gi, float* __restrict__ gh, float* __restrict__ gh2,
    const float* __restrict__ gi1s_t,
    const float* __restrict__ bhh1, const float* __restrict__ bhh2)
{
    __shared__ ushort_t As[128 * 40];
    __shared__ ushort_t Bs[64 * 40];
    const ushort_t* A; const ushort_t* B; float* C;
    const float* bias = nullptr; const float* cadd = nullptr;
    if (blockIdx.z == 0)      { A = h2b; B = Wih1h; C = gi;  cadd = gi1s_t; }
    else if (blockIdx.z == 1) { A = h1b; B = Whh1b; C = gh;  bias = bhh1; }
    else                      { A = h2b; B = Whh2b; C = gh2; bias = bhh2; }
    mfma_core<NF, false>(As, Bs, A, 1024, nullptr, B, 1024, C, 3072, nullptr,
                         bias, nullptr, cadd, (long)TSTEP * 3072, 1, 0,
                         3072, 1024, 0, blockIdx.x * (NF * 16));
}

// ---------------------------------------------------------------------------
// small helper kernels
// ---------------------------------------------------------------------------
__global__ void init_kernel(const int* __restrict__ caption,
                            int* __restrict__ tok_idx, int* __restrict__ crow20,
                            float* __restrict__ h12f, ushort_t* __restrict__ h12b)
{
    int idx = blockIdx.x * 256 + threadIdx.x;   // 262144 threads
    if (idx < BATCH * TSTEP) {
        int b = idx / TSTEP, t = idx % TSTEP;
        tok_idx[idx] = caption[b * MAXLEN + t];
        crow20[idx]  = b * MAXLEN + t;
    }
    h12f[idx] = 0.f;
    h12b[idx] = 0;
}

__global__ void sort_caption_kernel(const int* __restrict__ caption,
                                    const int* __restrict__ cap_len,
                                    float* __restrict__ out1)
{
    int i = threadIdx.x;
    if (i < BATCH) {
        int li = cap_len[i];
        int rank = 0;
        for (int j = 0; j < BATCH; j++) {
            int lj = cap_len[j];
            if (lj > li || (lj == li && j < i)) rank++;
        }
        for (int k = 0; k < TSTEP; k++)
            out1[rank * TSTEP + k] = (float)caption[i * MAXLEN + 1 + k];
    }
}

__global__ void vmean_kernel(const float* __restrict__ v,
                             float* __restrict__ vmean, ushort_t* __restrict__ vmeanb)
{
    int idx = blockIdx.x * 256 + threadIdx.x;   // BATCH*VDIM
    int b = idx >> 11, d = idx & (VDIM - 1);
    float s = 0.f;
    for (int o = 0; o < NOBJ; o++) s += v[((long)b * NOBJ + o) * VDIM + d];
    float m = s * (1.0f / 36.0f);
    vmean[idx] = m;
    vmeanb[idx] = f2b(m);
}

// strided (optionally row-gathered) f32 -> bf16 convert, 4 elems/thread
__global__ void conv_kernel(const float* __restrict__ src, long ld,
                            const int* __restrict__ rowidx,
                            ushort_t* __restrict__ dst, int rows, int cols)
{
    long idx4 = ((long)blockIdx.x * 256 + threadIdx.x) * 4;
    if (idx4 >= (long)rows * cols) return;
    int r = (int)(idx4 / cols);
    int c = (int)(idx4 % cols);
    long sr = rowidx ? rowidx[r] : r;
    float4 f = *(const float4*)(src + sr * ld + c);
    dst[idx4 + 0] = f2b(f.x);
    dst[idx4 + 1] = f2b(f.y);
    dst[idx4 + 2] = f2b(f.z);
    dst[idx4 + 3] = f2b(f.w);
}

// Wfc1 [1024x1024] -> Wfc1T bf16 (dst[n*1024+k] = src[k*1024+n])
__global__ void transpose_conv_kernel(const float* __restrict__ src,
                                      ushort_t* __restrict__ dst)
{
    __shared__ float tile[32][33];
    int bx = blockIdx.x, by = blockIdx.y;
    int lx = threadIdx.x & 31, ly = threadIdx.x >> 5;   // ly 0..7
    for (int i = 0; i < 32; i += 8)
        tile[ly + i][lx] = src[(long)(by * 32 + ly + i) * 1024 + bx * 32 + lx];
    __syncthreads();
    for (int i = 0; i < 32; i += 8)
        dst[(long)(bx * 32 + ly + i) * 1024 + by * 32 + lx] = f2b(tile[lx][ly + i]);
}

// bcat2[0:1024] = bq + Wq @ bfc1 ; bcat2[1024:4096] = bih2 + Wih2[:,2048:] @ bfc1
__global__ void bias_fold_kernel(const float* __restrict__ Wq,
                                 const float* __restrict__ Wih2,
                                 const float* __restrict__ bfc1,
                                 const float* __restrict__ bq,
                                 const float* __restrict__ bih2,
                                 float* __restrict__ bcat2)
{
    int wave = blockIdx.x * 4 + (threadIdx.x >> 6);
    int lane = threadIdx.x & 63;
    for (int n = wave; n < 4096; n += 256) {
        const float* wrow = (n < 1024) ? (Wq + (long)n * 1024)
                                       : (Wih2 + (long)(n - 1024) * 3072 + 2048);
        float s = 0.f;
        for (int j = lane; j < 1024; j += 64) s += wrow[j] * bfc1[j];
        for (int off = 32; off > 0; off >>= 1) s += __shfl_down(s, off);
        if (lane == 0) bcat2[n] = s + ((n < 1024) ? bq[n] : bih2[n - 1024]);
    }
}

// GRU combine: h = (1-z)*n + z*h ; writes f32 + bf16 (+ optional H2A bf16 store)
__global__ void gru_kernel(const float* __restrict__ gi, const float* __restrict__ gh,
                           float* __restrict__ h, ushort_t* __restrict__ hb,
                           ushort_t* __restrict__ hstore, int t)
{
    int idx = blockIdx.x * 256 + threadIdx.x;   // BATCH*HID
    int b = idx >> 10, j = idx & (HID - 1);
    const float* gib = gi + (long)b * 3 * HID;
    const float* ghb = gh + (long)b * 3 * HID;
    float ir = gib[j], iz = gib[HID + j], in_ = gib[2 * HID + j];
    float hr = ghb[j], hz = ghb[HID + j], hn  = ghb[2 * HID + j];
    float r = 1.f / (1.f + expf(-(ir + hr)));
    float z = 1.f / (1.f + expf(-(iz + hz)));
    float n = tanhf(in_ + r * hn);
    float hnew = (1.f - z) * n + z * h[idx];
    h[idx] = hnew;
    ushort_t hq = f2b(hnew);
    hb[idx] = hq;
    if (hstore) hstore[((long)(b * TSTEP + t) << 10) | j] = hq;
}

// attention: logits (vw.q) -> softmax(36) -> alpha, att_v(bf16)
__global__ __launch_bounds__(256) void attention_kernel(
    const ushort_t* __restrict__ vwb, const float* __restrict__ qgi2,
    const float* __restrict__ v, const int* __restrict__ cap_len, int t,
    ushort_t* __restrict__ x2v, float* __restrict__ alpha)
{
    int b = blockIdx.x;
    __shared__ float att_s[NOBJ];
    int tid = threadIdx.x;
    int lane = tid & 63, w = tid >> 6;
    const float* qb = qgi2 + (long)b * 4096;

    for (int o = w; o < NOBJ; o += 4) {
        const ushort_t* vwo = vwb + ((long)b * NOBJ + o) * HID;
        float s = 0.f;
        for (int hh = lane; hh < HID; hh += 64) s += b2f(vwo[hh]) * qb[hh];
        for (int off = 32; off > 0; off >>= 1) s += __shfl_down(s, off);
        if (lane == 0) att_s[o] = s;
    }
    __syncthreads();
    if (tid == 0) {
        float mx = att_s[0];
        for (int o = 1; o < NOBJ; o++) mx = fmaxf(mx, att_s[o]);
        float sum = 0.f;
        for (int o = 0; o < NOBJ; o++) { float e = expf(att_s[o] - mx); att_s[o] = e; sum += e; }
        float inv = 1.f / sum;
        for (int o = 0; o < NOBJ; o++) att_s[o] *= inv;
    }
    __syncthreads();
    bool m = (t < cap_len[b] - 1);
    if (tid < NOBJ) alpha[((long)b * MAXLEN + t) * NOBJ + tid] = m ? att_s[tid] : 0.f;
    for (int d = tid; d < VDIM; d += 256) {
        float s = 0.f;
        for (int o = 0; o < NOBJ; o++) s += att_s[o] * v[((long)b * NOBJ + o) * VDIM + d];
        x2v[(long)b * VDIM + d] = f2b(s);
    }
}

// row softmax over NTOKEN; masked rows -> uniform; t==19 alpha rows -> 0
__global__ __launch_bounds__(256) void softmax_kernel(float* __restrict__ predict,
                                                      float* __restrict__ alpha,
                                                      const int* __restrict__ cap_len)
{
    __shared__ float sred[4];
    int row = blockIdx.x;                 // b*20 + t
    int b = row / MAXLEN, t = row % MAXLEN;
    float* p = predict + (long)row * NTOKEN;
    int tid = threadIdx.x;
    int dec = cap_len[b] - 1;
    if (t >= dec) {
        const float u = 1.0f / (float)NTOKEN;
        for (int i = tid; i < NTOKEN; i += 256) p[i] = u;
        if (t == MAXLEN - 1 && tid < NOBJ) alpha[(long)row * NOBJ + tid] = 0.f;
        return;
    }
    float mx = -3.4e38f;
    for (int i = tid; i < NTOKEN; i += 256) mx = fmaxf(mx, p[i]);
    for (int off = 32; off > 0; off >>= 1) mx = fmaxf(mx, __shfl_down(mx, off));
    if ((tid & 63) == 0) sred[tid >> 6] = mx;
    __syncthreads();
    mx = fmaxf(fmaxf(sred[0], sred[1]), fmaxf(sred[2], sred[3]));
    __syncthreads();
    float s = 0.f;
    for (int i = tid; i < NTOKEN; i += 256) s += expf(p[i] - mx);
    for (int off = 32; off > 0; off >>= 1) s += __shfl_down(s, off);
    if ((tid & 63) == 0) sred[tid >> 6] = s;
    __syncthreads();
    s = sred[0] + sred[1] + sred[2] + sred[3];
    float inv = 1.f / s;
    for (int i = tid; i < NTOKEN; i += 256) p[i] = expf(p[i] - mx) * inv;
}

// ---------------------------------------------------------------------------
extern "C" void kernel_launch(void* const* d_in, const int* in_sizes, int n_in,
                              void* d_out, int out_size, void* d_ws, size_t ws_size,
                              hipStream_t stream)
{
    const float* v       = (const float*)d_in[0];
    const int*   caption = (const int*)  d_in[1];
    const int*   cap_len = (const int*)  d_in[2];
    const float* emb     = (const float*)d_in[3];
    const float* Wih1    = (const float*)d_in[4];
    const float* Whh1    = (const float*)d_in[5];
    const float* bih1    = (const float*)d_in[6];
    const float* bhh1    = (const float*)d_in[7];
    const float* Wih2    = (const float*)d_in[8];
    const float* Whh2    = (const float*)d_in[9];
    const float* bih2    = (const float*)d_in[10];
    const float* bhh2    = (const float*)d_in[11];
    const float* Wfc1    = (const float*)d_in[12];
    const float* bfc1    = (const float*)d_in[13];
    const float* Wfc2    = (const float*)d_in[14];
    const float* bfc2    = (const float*)d_in[15];
    const float* Wv      = (const float*)d_in[16];
    const float* bv      = (const float*)d_in[17];
    const float* Wq      = (const float*)d_in[18];
    const float* bq      = (const float*)d_in[19];
    const float* Wa      = (const float*)d_in[20];
    // ba cancels in softmax

    // ---- workspace layout ----
    float* f32base = (float*)d_ws;
    float* gvm   = f32base;              // 128*3072
    float* gi1s  = gvm   + 393216;       // 2432*3072
    float* h1    = gi1s  + 7471104;      // 128*1024  (h1,h2 contiguous)
    float* h2    = h1    + 131072;
    float* gi    = h2    + 131072;       // 128*3072
    float* gh    = gi    + 393216;
    float* gh2   = gh    + 393216;
    float* qgi2  = gh2   + 393216;       // 128*4096
    float* vmean = qgi2  + 524288;       // 128*2048
    float* bcat2 = vmean + 262144;       // 4096
    ushort_t* ub = (ushort_t*)(bcat2 + 4096);
    ushort_t* Wih1h = ub;                 // 3072*1024
    ushort_t* Wih1c = Wih1h + 3145728;    // 3072*1024
    ushort_t* Whh1b = Wih1c + 3145728;    // 3072*1024
    ushort_t* Whh2b = Whh1b + 3145728;    // 3072*1024
    ushort_t* Wih2v = Whh2b + 3145728;    // 3072*2048
    ushort_t* Wcat2 = Wih2v + 6291456;    // 4096*1024
    ushort_t* Wfc2b = Wcat2 + 4194304;    // 15000*1024
    ushort_t* vw_bf = Wfc2b + 15360000;   // 4608*1024
    ushort_t* H2Ab  = vw_bf + 4718592;    // 2432*1024
    ushort_t* h1b   = H2Ab  + 2490368;    // 128*1024 (h1b,h2b contiguous)
    ushort_t* h2b   = h1b   + 131072;
    ushort_t* x2v   = h2b   + 131072;     // 128*2048
    ushort_t* vmeanb= x2v   + 262144;     // 128*2048
    ushort_t* TEMP  = vmeanb+ 262144;     // 11534336 max
    // TEMP sub-uses (sequential in stream):
    ushort_t* vb     = TEMP;              // 4608*2048
    ushort_t* Wvb    = TEMP + 9437184;    // 1024*2048
    ushort_t* Wqb    = TEMP;              // 1024*1024
    ushort_t* Wih2hb = TEMP + 1048576;    // 3072*1024
    ushort_t* Wfc1T  = TEMP + 4194304;    // 1024*1024
    ushort_t* Wih1m  = TEMP;              // 3072*2048
    ushort_t* Acap   = TEMP;              // 2432*1024
    int* tok_idx = (int*)(TEMP + 11534336);
    int* crow20  = tok_idx + BATCH * TSTEP;

    float* out     = (float*)d_out;
    float* predict = out;                                   // 128*20*15000
    float* out1    = out + (long)BATCH * MAXLEN * NTOKEN;   // 128*19
    float* alpha   = out1 + (long)BATCH * TSTEP;            // 128*20*36

    #define CONV(src, ld, rowidx, dst, rows, cols) \
        conv_kernel<<<(int)(((long)(rows)*(cols)/4 + 255)/256), 256, 0, stream>>>( \
            src, ld, rowidx, dst, rows, cols)

    // ---- prologue ----
    init_kernel<<<1024, 256, 0, stream>>>(caption, tok_idx, crow20, h1, h1b);
    sort_caption_kernel<<<1, 128, 0, stream>>>(caption, cap_len, out1);
    vmean_kernel<<<(BATCH * VDIM) / 256, 256, 0, stream>>>(v, vmean, vmeanb);

    CONV(Wih1,        4096, nullptr, Wih1h, 3072, 1024);
    CONV(Wih1 + 3072, 4096, nullptr, Wih1c, 3072, 1024);
    CONV(Whh1,        1024, nullptr, Whh1b, 3072, 1024);
    CONV(Whh2,        1024, nullptr, Whh2b, 3072, 1024);
    CONV(Wih2,        3072, nullptr, Wih2v, 3072, 2048);
    CONV(Wfc2,        1024, nullptr, Wfc2b, NTOKEN, 1024);

    // vw = relu(v @ Wv^T + bv) * Wa  -> bf16 [4608 x 1024]
    CONV(v,  2048, nullptr, vb,  4608, 2048);
    CONV(Wv, 2048, nullptr, Wvb, 1024, 2048);
    mfma_gemm<4, true><<<dim3(16, 36), 256, 0, stream>>>(
        vb, 2048, nullptr, Wvb, 2048, vw_bf, 1024, nullptr,
        bv, Wa, nullptr, 0, 1, 1024, 1024, 2048);

    // folded weights: Wcat2 = [Wq@Wfc1 ; Wih2[:,2048:]@Wfc1]
    CONV(Wq,          1024, nullptr, Wqb,    1024, 1024);
    CONV(Wih2 + 2048, 3072, nullptr, Wih2hb, 3072, 1024);
    transpose_conv_kernel<<<dim3(32, 32), 256, 0, stream>>>(Wfc1, Wfc1T);
    mfma_gemm<4, true><<<dim3(16, 8), 256, 0, stream>>>(
        Wqb, 1024, nullptr, Wfc1T, 1024, Wcat2, 1024, nullptr,
        nullptr, nullptr, nullptr, 0, 1, 0, 1024, 1024);
    mfma_gemm<4, true><<<dim3(16, 24), 256, 0, stream>>>(
        Wih2hb, 1024, nullptr, Wfc1T, 1024, Wcat2 + 1048576, 1024, nullptr,
        nullptr, nullptr, nullptr, 0, 1, 0, 1024, 1024);
    bias_fold_kernel<<<64, 256, 0, stream>>>(Wq, Wih2, bfc1, bq, bih2, bcat2);

    // gvm = vmean @ Wih1[:,1024:3072]^T + bih1  (f32 [128 x 3072])
    CONV(Wih1 + 1024, 4096, nullptr, Wih1m, 3072, 2048);
    mfma_gemm<4, false><<<dim3(48, 1), 256, 0, stream>>>(
        vmeanb, 2048, nullptr, Wih1m, 2048, gvm, 3072, nullptr,
        bih1, nullptr, nullptr, 0, 1, 0, 3072, 2048);

    // gi1s[b*19+t] = emb[cap[b,t]] @ Wih1[:,3072:]^T + gvm[b]
    CONV(emb, 1024, tok_idx, Acap, 2432, 1024);
    mfma_gemm<4, false><<<dim3(48, 19), 256, 0, stream>>>(
        Acap, 1024, nullptr, Wih1c, 1024, gi1s, 3072, nullptr,
        nullptr, nullptr, gvm, 3072, TSTEP, 0, 3072, 1024);

    // ---- recurrent loop ----
    for (int t = 0; t < TSTEP; t++) {
        step3_kernel<2><<<dim3(96, 1, 3), 256, 0, stream>>>(
            h1b, h2b, Wih1h, Whh1b, Whh2b, gi, gh, gh2,
            gi1s + (long)t * 3072, bhh1, bhh2);
        gru_kernel<<<512, 256, 0, stream>>>(gi, gh, h1, h1b, nullptr, t);
        // [q | gi2_h] = h1' @ Wcat2^T + bcat2, relu on first 1024 cols
        mfma_gemm<2, false><<<dim3(128, 1), 256, 0, stream>>>(
            h1b, 1024, nullptr, Wcat2, 1024, qgi2, 4096, nullptr,
            bcat2, nullptr, nullptr, 0, 1, 1024, 4096, 1024);
        attention_kernel<<<BATCH, 256, 0, stream>>>(
            vw_bf, qgi2, v, cap_len, t, x2v, alpha);
        // gi2 = att_v @ Wih2[:, :2048]^T + gi2_h
        mfma_gemm<2, false><<<dim3(96, 1), 256, 0, stream>>>(
            x2v, 2048, nullptr, Wih2v, 2048, gi, 3072, nullptr,
            nullptr, nullptr, qgi2 + 1024, 4096, 1, 0, 3072, 2048);
        gru_kernel<<<512, 256, 0, stream>>>(gi, gh2, h2, h2b, H2Ab, t);
    }

    // ---- epilogue ----
    mfma_gemm<4, false><<<dim3(235, 19), 256, 0, stream>>>(
        H2Ab, 1024, nullptr, Wfc2b, 1024, predict, NTOKEN, crow20,
        bfc2, nullptr, nullptr, 0, 1, 0, NTOKEN, 1024);
    softmax_kernel<<<BATCH * MAXLEN, 256, 0, stream>>>(predict, alpha, cap_len);
    #undef CONV
}